// Round 1
// baseline (135.693 us; speedup 1.0000x reference)
//
#include <hip/hip_runtime.h>

#define HDIM 128
#define NPOS 1024
#define NCOL 512
#define LN_EPS 1e-3f
#define NBLK 256

// ---------------------------------------------------------------------------
// Workspace layout (floats):
//   AcT  [128][1024]  centered seq-side A, k-major
//   BcT  [128][512]   centered col-side B, k-major
//   p[1024] v[1024] q[512] w[512]
//   sums: rowsum[1024] + segsum[n_seq*512]  (atomics, zeroed in phase 1)
//   E    [1024][512]
//   segid[1024] (int)
//   bar  (uint)  grid-barrier counter (zeroed by 4-B memset node each replay)
// ---------------------------------------------------------------------------

#define AS_STR 36
#define BS_STR 68

union FusedSmem {
    struct {                       // phase 1
        float xs[4][HDIM];
        float ds[4][HDIM];
        float partm[8], partp[8], partv[8], mus[4];
    } p1;
    struct { float As[128 * AS_STR]; float Bs[128 * BS_STR]; } s;   // phase 2 tiles
    struct { float comb[8 * 256]; float redr[512]; float redc[1024]; } r; // phase 2 reduce
};

__device__ __forceinline__ int seg_of(int i, const int* __restrict__ lens, int n_seq) {
    int cum = 0;
    for (int s = 0; s < n_seq; ++s) { cum += lens[s]; if (i < cum) return s; }
    return n_seq - 1;
}

// Monotonic-counter grid barrier. All 256 blocks are co-resident
// (grid == #CUs, __launch_bounds__(512,2) caps VGPR so 1 block/CU fits).
// Agent-scope release/acquire gives cross-XCD L2 writeback/invalidate,
// replacing the implicit fences at the old kernel boundaries.
__device__ __forceinline__ void grid_sync(unsigned int* bar, unsigned int need) {
    __syncthreads();                       // drains vmcnt: all block stores in L2
    if (threadIdx.x == 0) {
        __hip_atomic_fetch_add(bar, 1u, __ATOMIC_RELEASE, __HIP_MEMORY_SCOPE_AGENT);
        while (__hip_atomic_load(bar, __ATOMIC_ACQUIRE, __HIP_MEMORY_SCOPE_AGENT) < need) {}
    }
    __syncthreads();
}

extern "C" __global__ void __launch_bounds__(512, 2)
fused_all(const float* __restrict__ seq_feat, const float* __restrict__ col_feat,
          const float* __restrict__ Ws, const float* __restrict__ bsv,
          const float* __restrict__ Wc, const float* __restrict__ bcv,
          const float* __restrict__ Wm, const float* __restrict__ bmv,
          const float* __restrict__ gam, const float* __restrict__ Wo,
          const int* __restrict__ lens, int n_seq,
          float* __restrict__ AcT, float* __restrict__ BcT,
          float* __restrict__ p_arr, float* __restrict__ v_arr,
          float* __restrict__ q_arr, float* __restrict__ w_arr,
          float* __restrict__ sums, int* __restrict__ segid,
          float* __restrict__ E, float* __restrict__ out,
          unsigned int* __restrict__ bar)
{
    __shared__ FusedSmem sm;
    const int t = threadIdx.x;
    const int b = blockIdx.x;

    // =================== phase 1: per-row precompute (old k1) ===================
    {
        const int h    = t & 127;
        const int r    = t >> 7;
        const int wv   = t >> 6;
        const int lane = t & 63;

        // housekeeping: zero accumulators + fill segid LUT
        {
            const int nsums = NPOS + n_seq * NCOL;
            int idx = b * 512 + t;
            if (idx < nsums) sums[idx] = 0.f;
            int idx2 = idx - nsums;
            if (idx2 >= 0 && idx2 < NPOS) segid[idx2] = seg_of(idx2, lens, n_seq);
        }

        for (int pass = 0; pass < 2; ++pass) {
            const int unit = b + NBLK * pass;          // 384 units over 256 blocks
            if (unit < (NPOS + NCOL) / 4) {
                const bool  is_seq = (unit < NPOS / 4);
                const int   i0 = (is_seq ? unit : unit - NPOS / 4) * 4;
                const float* X  = is_seq ? seq_feat : col_feat;
                const float* W1 = is_seq ? Ws : Wc;
                const float* b1 = is_seq ? bsv : bcv;

                if (t < 128) {
                    int rr = t >> 5, k4 = (t & 31) * 4;
                    *(float4*)&sm.p1.xs[rr][k4] = *(const float4*)&X[(i0 + rr) * HDIM + k4];
                }
                __syncthreads();

                // stage 1: d = relu(x_r . W1[:,h] + b1[h])
                float d;
                {
                    float a0 = 0.f, a1 = 0.f, a2 = 0.f, a3 = 0.f;
                    #pragma unroll 8
                    for (int k = 0; k < HDIM; k += 4) {
                        float4 x = *(const float4*)&sm.p1.xs[r][k];
                        float w0 = W1[(k + 0) * HDIM + h];
                        float w1 = W1[(k + 1) * HDIM + h];
                        float w2 = W1[(k + 2) * HDIM + h];
                        float w3 = W1[(k + 3) * HDIM + h];
                        a0 += x.x * w0; a1 += x.y * w1; a2 += x.z * w2; a3 += x.w * w3;
                    }
                    d = fmaxf(b1[h] + ((a0 + a1) + (a2 + a3)), 0.f);
                }
                sm.p1.ds[r][h] = d;
                __syncthreads();

                // stage 2: aa = d_r . Wm[:,h] (+ bm on col side)
                float aa;
                {
                    float a0 = 0.f, a1 = 0.f, a2 = 0.f, a3 = 0.f;
                    #pragma unroll 8
                    for (int k = 0; k < HDIM; k += 4) {
                        float4 x = *(const float4*)&sm.p1.ds[r][k];
                        float w0 = Wm[(k + 0) * HDIM + h];
                        float w1 = Wm[(k + 1) * HDIM + h];
                        float w2 = Wm[(k + 2) * HDIM + h];
                        float w3 = Wm[(k + 3) * HDIM + h];
                        a0 += x.x * w0; a1 += x.y * w1; a2 += x.z * w2; a3 += x.w * w3;
                    }
                    aa = (is_seq ? 0.f : bmv[h]) + ((a0 + a1) + (a2 + a3));
                }

                // row mean
                {
                    float s = aa;
                    #pragma unroll
                    for (int off = 32; off; off >>= 1) s += __shfl_xor(s, off, 64);
                    if (lane == 0) sm.p1.partm[wv] = s;
                }
                __syncthreads();
                if (t < 4) sm.p1.mus[t] = (sm.p1.partm[2 * t] + sm.p1.partm[2 * t + 1]) * (1.f / HDIM);
                __syncthreads();

                const float a  = aa - sm.p1.mus[r];
                const float gw = gam[h] * Wo[h];

                // p = dot(a, gamma*Wo), v = mean(a^2)
                {
                    float sp = a * gw, sv = a * a;
                    #pragma unroll
                    for (int off = 32; off; off >>= 1) {
                        sp += __shfl_xor(sp, off, 64);
                        sv += __shfl_xor(sv, off, 64);
                    }
                    if (lane == 0) { sm.p1.partp[wv] = sp; sm.p1.partv[wv] = sv; }
                }
                sm.p1.xs[r][h] = a;     // reuse xs for transpose staging
                __syncthreads();
                if (t < 4) {
                    (is_seq ? p_arr : q_arr)[i0 + t] = sm.p1.partp[2 * t] + sm.p1.partp[2 * t + 1];
                    (is_seq ? v_arr : w_arr)[i0 + t] = (sm.p1.partv[2 * t] + sm.p1.partv[2 * t + 1]) * (1.f / HDIM);
                }
                if (t < 128) {
                    float4 st = make_float4(sm.p1.xs[0][t], sm.p1.xs[1][t], sm.p1.xs[2][t], sm.p1.xs[3][t]);
                    if (is_seq) *(float4*)&AcT[t * NPOS + i0] = st;
                    else        *(float4*)&BcT[t * NCOL + i0] = st;
                }
            }
            __syncthreads();   // LDS reusable for next pass
        }
    }
    grid_sync(bar, 1u * NBLK);

    // =================== phase 2: fused GEMM + exp + sums (old k2) ===================
    float* rowsum = sums;
    float* segsum = sums + NPOS;
    {
        const int tt = t & 255;
        const int tc = tt & 15;          // col group (4 cols)
        const int tr = tt >> 4;          // row group (2 rows)
        const int kbase = (t >> 8) * 64;
        const int i0 = (b >> 3) * 32;
        const int j0 = (b & 7) * 64;

        #pragma unroll
        for (int u = 0; u < 2; ++u) {
            int fid = t + 512 * u;
            int k = fid >> 3, m4 = fid & 7;
            *(float4*)&sm.s.As[k * AS_STR + 4 * m4] = *(const float4*)&AcT[k * NPOS + i0 + 4 * m4];
        }
        #pragma unroll
        for (int u = 0; u < 4; ++u) {
            int fid = t + 512 * u;
            int k = fid >> 4, n4 = fid & 15;
            *(float4*)&sm.s.Bs[k * BS_STR + 4 * n4] = *(const float4*)&BcT[k * NCOL + j0 + 4 * n4];
        }
        __syncthreads();

        float acc[8] = {0.f, 0.f, 0.f, 0.f, 0.f, 0.f, 0.f, 0.f};
        #pragma unroll 4
        for (int k = kbase; k < kbase + 64; ++k) {
            float2 a2 = *(const float2*)&sm.s.As[k * AS_STR + 2 * tr];
            float4 b4 = *(const float4*)&sm.s.Bs[k * BS_STR + 4 * tc];
            acc[0] += a2.x * b4.x; acc[1] += a2.x * b4.y; acc[2] += a2.x * b4.z; acc[3] += a2.x * b4.w;
            acc[4] += a2.y * b4.x; acc[5] += a2.y * b4.y; acc[6] += a2.y * b4.z; acc[7] += a2.y * b4.w;
        }

        const int seg_lo = segid[i0];
        const int seg_hi = segid[i0 + 31];
        __syncthreads();   // As/Bs done; union region reusable

        if (t >= 256) {
            #pragma unroll
            for (int j = 0; j < 8; ++j) sm.r.comb[j * 256 + tt] = acc[j];
        }
        __syncthreads();

        float e[2][4];
        if (t < 256) {
            #pragma unroll
            for (int j = 0; j < 8; ++j) acc[j] += sm.r.comb[j * 256 + tt];

            const int jj = j0 + 4 * tc;
            float4 q4 = *(const float4*)&q_arr[jj];
            float4 w4 = *(const float4*)&w_arr[jj];
            float rs[2];
            #pragma unroll
            for (int mm = 0; mm < 2; ++mm) {
                const int i = i0 + 2 * tr + mm;
                const float pi = p_arr[i];
                const float vi = v_arr[i];
                e[mm][0] = __expf((pi + q4.x) * rsqrtf(vi + w4.x + acc[4*mm+0] * (2.f/HDIM) + LN_EPS));
                e[mm][1] = __expf((pi + q4.y) * rsqrtf(vi + w4.y + acc[4*mm+1] * (2.f/HDIM) + LN_EPS));
                e[mm][2] = __expf((pi + q4.z) * rsqrtf(vi + w4.z + acc[4*mm+2] * (2.f/HDIM) + LN_EPS));
                e[mm][3] = __expf((pi + q4.w) * rsqrtf(vi + w4.w + acc[4*mm+3] * (2.f/HDIM) + LN_EPS));
                rs[mm] = e[mm][0] + e[mm][1] + e[mm][2] + e[mm][3];
                *(float4*)&E[i * NCOL + jj] = make_float4(e[mm][0], e[mm][1], e[mm][2], e[mm][3]);
            }
            sm.r.redr[(2 * tr + 0) * 16 + tc] = rs[0];
            sm.r.redr[(2 * tr + 1) * 16 + tc] = rs[1];
            #pragma unroll
            for (int u = 0; u < 4; ++u)
                sm.r.redc[(4 * tc + u) * 16 + tr] = e[0][u] + e[1][u];
        }
        __syncthreads();

        if (t < 32) {
            float s = 0.f;
            #pragma unroll
            for (int m = 0; m < 16; ++m) s += sm.r.redr[t * 16 + m];
            atomicAdd(&rowsum[i0 + t], s);
        } else if (t >= 32 && t < 96 && seg_lo == seg_hi) {
            int c = t - 32;
            float s = 0.f;
            #pragma unroll
            for (int m = 0; m < 16; ++m) s += sm.r.redc[c * 16 + m];
            atomicAdd(&segsum[seg_lo * NCOL + j0 + c], s);
        }
        if (seg_lo != seg_hi && t < 256) {
            // generic path: tile crosses a segment boundary (not hit for 8x128)
            #pragma unroll
            for (int mm = 0; mm < 2; ++mm) {
                const int i = i0 + 2 * tr + mm;
                const int sg = segid[i];
                #pragma unroll
                for (int u = 0; u < 4; ++u)
                    atomicAdd(&segsum[sg * NCOL + j0 + 4 * tc + u], e[mm][u]);
            }
        }
    }
    grid_sync(bar, 2u * NBLK);

    // =================== phase 3: out = M_c + M_s - M_c*M_s (old k3) ===================
    {
        const int gid = b * 512 + t;              // 131072 float4 groups
        const int i = gid >> 7;
        const int j = (gid & 127) * 4;

        float4 e4 = *(const float4*)&E[i * NCOL + j];
        const float invr = 1.f / rowsum[i];
        const int sg = segid[i];
        float4 s4 = *(const float4*)&segsum[sg * NCOL + j];

        float4 o;
        { float mc = e4.x * invr, ms = e4.x / s4.x; o.x = mc + ms - mc * ms; }
        { float mc = e4.y * invr, ms = e4.y / s4.y; o.y = mc + ms - mc * ms; }
        { float mc = e4.z * invr, ms = e4.z / s4.z; o.z = mc + ms - mc * ms; }
        { float mc = e4.w * invr, ms = e4.w / s4.w; o.w = mc + ms - mc * ms; }
        *(float4*)&out[i * NCOL + j] = o;
    }
}

// ===========================================================================
extern "C" void kernel_launch(void* const* d_in, const int* in_sizes, int n_in,
                              void* d_out, int out_size, void* d_ws, size_t ws_size,
                              hipStream_t stream) {
    const float* seq_feat = (const float*)d_in[0];
    const float* col_feat = (const float*)d_in[1];
    const int*   lens     = (const int*)d_in[2];
    const float* Ws   = (const float*)d_in[3];
    const float* bs   = (const float*)d_in[4];
    const float* Wc   = (const float*)d_in[5];
    const float* bc   = (const float*)d_in[6];
    const float* Wm   = (const float*)d_in[7];
    const float* bm   = (const float*)d_in[8];
    const float* gam  = (const float*)d_in[9];
    // d_in[10] = beta, d_in[12] = bo: cancel in both normalizations
    const float* Wo   = (const float*)d_in[11];
    float* out = (float*)d_out;
    const int n_seq = in_sizes[2];

    float* ws     = (float*)d_ws;
    float* AcT    = ws;                    // 128*1024
    float* BcT    = AcT + HDIM * NPOS;     // 128*512
    float* p      = BcT + HDIM * NCOL;     // 1024
    float* v      = p + NPOS;              // 1024
    float* q      = v + NPOS;              // 512
    float* w      = q + NCOL;              // 512
    float* sums   = w + NCOL;              // rowsum 1024 + segsum n_seq*512
    float* E      = sums + NPOS + n_seq * NCOL; // 1024*512
    int*   segid  = (int*)(E + NPOS * NCOL);    // 1024 ints
    unsigned int* bar = (unsigned int*)(segid + NPOS);

    // zero the grid-barrier counter each replay (workspace is re-poisoned)
    hipMemsetAsync(bar, 0, sizeof(unsigned int), stream);
    hipLaunchKernelGGL(fused_all, dim3(NBLK), dim3(512), 0, stream,
                       seq_feat, col_feat, Ws, bs, Wc, bc, Wm, bm, gam, Wo,
                       lens, n_seq, AcT, BcT, p, v, q, w, sums, segid, E, out, bar);
}

// Round 2
// 123.165 us; speedup vs baseline: 1.1017x; 1.1017x over previous
//
#include <hip/hip_runtime.h>

#define HDIM 128
#define NPOS 1024
#define NCOL 512
#define LN_EPS 1e-3f
#define NBLK 256

// ---------------------------------------------------------------------------
// Workspace layout (floats):
//   AcT  [128][1024]  centered seq-side A, k-major
//   BcT  [128][512]   centered col-side B, k-major
//   p[1024] v[1024] q[512] w[512]
//   sums: rowsum[1024] + segsum[n_seq*512]  (atomics, zeroed in phase 1)
//   E    [1024][512]
//   segid[1024] (int)
//   bar  (uint)  grid-barrier counter (zeroed by 4-B memset node each replay)
// ---------------------------------------------------------------------------

#define AS_STR 36
#define BS_STR 68

union FusedSmem {
    struct {                       // phase 1
        float xs[4][HDIM];
        float ds[4][HDIM];
        float partm[8], partp[8], partv[8], mus[4];
    } p1;
    struct { float As[128 * AS_STR]; float Bs[128 * BS_STR]; } s;   // phase 2 tiles
    struct { float comb[8 * 256]; float redr[512]; float redc[1024]; } r; // phase 2 reduce
};

__device__ __forceinline__ int seg_of(int i, const int* __restrict__ lens, int n_seq) {
    int cum = 0;
    for (int s = 0; s < n_seq; ++s) { cum += lens[s]; if (i < cum) return s; }
    return n_seq - 1;
}

// Monotonic-counter grid barrier, cooperative-groups style.
// KEY FIX vs previous round: the spin polls with a RELAXED load + s_sleep
// backoff (no per-iteration buffer_inv), and exactly ONE acquire operation
// executes after the count is reached. The release fetch_add emits one L2
// writeback per block; the final acquire load emits one invalidate per block.
// Previous version acquired on EVERY poll iteration -> 256 spinners issuing
// continuous cache-invalidates, starving the still-computing blocks (58us of
// the 68.6us kernel time was this spin storm).
__device__ __forceinline__ void grid_sync(unsigned int* bar, unsigned int need) {
    __syncthreads();                       // drains this block's stores to L2
    if (threadIdx.x == 0) {
        __hip_atomic_fetch_add(bar, 1u, __ATOMIC_RELEASE, __HIP_MEMORY_SCOPE_AGENT);
        while (__hip_atomic_load(bar, __ATOMIC_RELAXED, __HIP_MEMORY_SCOPE_AGENT) < need)
            __builtin_amdgcn_s_sleep(4);   // ~256-cycle backoff per poll
        // single acquire: invalidate stale L1/L2 lines once, after arrival
        (void)__hip_atomic_load(bar, __ATOMIC_ACQUIRE, __HIP_MEMORY_SCOPE_AGENT);
    }
    __syncthreads();
}

extern "C" __global__ void __launch_bounds__(512, 2)
fused_all(const float* __restrict__ seq_feat, const float* __restrict__ col_feat,
          const float* __restrict__ Ws, const float* __restrict__ bsv,
          const float* __restrict__ Wc, const float* __restrict__ bcv,
          const float* __restrict__ Wm, const float* __restrict__ bmv,
          const float* __restrict__ gam, const float* __restrict__ Wo,
          const int* __restrict__ lens, int n_seq,
          float* __restrict__ AcT, float* __restrict__ BcT,
          float* __restrict__ p_arr, float* __restrict__ v_arr,
          float* __restrict__ q_arr, float* __restrict__ w_arr,
          float* __restrict__ sums, int* __restrict__ segid,
          float* __restrict__ E, float* __restrict__ out,
          unsigned int* __restrict__ bar)
{
    __shared__ FusedSmem sm;
    const int t = threadIdx.x;
    const int b = blockIdx.x;

    // =================== phase 1: per-row precompute (old k1) ===================
    {
        const int h    = t & 127;
        const int r    = t >> 7;
        const int wv   = t >> 6;
        const int lane = t & 63;

        // housekeeping: zero accumulators + fill segid LUT
        {
            const int nsums = NPOS + n_seq * NCOL;
            int idx = b * 512 + t;
            if (idx < nsums) sums[idx] = 0.f;
            int idx2 = idx - nsums;
            if (idx2 >= 0 && idx2 < NPOS) segid[idx2] = seg_of(idx2, lens, n_seq);
        }

        for (int pass = 0; pass < 2; ++pass) {
            const int unit = b + NBLK * pass;          // 384 units over 256 blocks
            if (unit < (NPOS + NCOL) / 4) {
                const bool  is_seq = (unit < NPOS / 4);
                const int   i0 = (is_seq ? unit : unit - NPOS / 4) * 4;
                const float* X  = is_seq ? seq_feat : col_feat;
                const float* W1 = is_seq ? Ws : Wc;
                const float* b1 = is_seq ? bsv : bcv;

                if (t < 128) {
                    int rr = t >> 5, k4 = (t & 31) * 4;
                    *(float4*)&sm.p1.xs[rr][k4] = *(const float4*)&X[(i0 + rr) * HDIM + k4];
                }
                __syncthreads();

                // stage 1: d = relu(x_r . W1[:,h] + b1[h])
                float d;
                {
                    float a0 = 0.f, a1 = 0.f, a2 = 0.f, a3 = 0.f;
                    #pragma unroll 8
                    for (int k = 0; k < HDIM; k += 4) {
                        float4 x = *(const float4*)&sm.p1.xs[r][k];
                        float w0 = W1[(k + 0) * HDIM + h];
                        float w1 = W1[(k + 1) * HDIM + h];
                        float w2 = W1[(k + 2) * HDIM + h];
                        float w3 = W1[(k + 3) * HDIM + h];
                        a0 += x.x * w0; a1 += x.y * w1; a2 += x.z * w2; a3 += x.w * w3;
                    }
                    d = fmaxf(b1[h] + ((a0 + a1) + (a2 + a3)), 0.f);
                }
                sm.p1.ds[r][h] = d;
                __syncthreads();

                // stage 2: aa = d_r . Wm[:,h] (+ bm on col side)
                float aa;
                {
                    float a0 = 0.f, a1 = 0.f, a2 = 0.f, a3 = 0.f;
                    #pragma unroll 8
                    for (int k = 0; k < HDIM; k += 4) {
                        float4 x = *(const float4*)&sm.p1.ds[r][k];
                        float w0 = Wm[(k + 0) * HDIM + h];
                        float w1 = Wm[(k + 1) * HDIM + h];
                        float w2 = Wm[(k + 2) * HDIM + h];
                        float w3 = Wm[(k + 3) * HDIM + h];
                        a0 += x.x * w0; a1 += x.y * w1; a2 += x.z * w2; a3 += x.w * w3;
                    }
                    aa = (is_seq ? 0.f : bmv[h]) + ((a0 + a1) + (a2 + a3));
                }

                // row mean
                {
                    float s = aa;
                    #pragma unroll
                    for (int off = 32; off; off >>= 1) s += __shfl_xor(s, off, 64);
                    if (lane == 0) sm.p1.partm[wv] = s;
                }
                __syncthreads();
                if (t < 4) sm.p1.mus[t] = (sm.p1.partm[2 * t] + sm.p1.partm[2 * t + 1]) * (1.f / HDIM);
                __syncthreads();

                const float a  = aa - sm.p1.mus[r];
                const float gw = gam[h] * Wo[h];

                // p = dot(a, gamma*Wo), v = mean(a^2)
                {
                    float sp = a * gw, sv = a * a;
                    #pragma unroll
                    for (int off = 32; off; off >>= 1) {
                        sp += __shfl_xor(sp, off, 64);
                        sv += __shfl_xor(sv, off, 64);
                    }
                    if (lane == 0) { sm.p1.partp[wv] = sp; sm.p1.partv[wv] = sv; }
                }
                sm.p1.xs[r][h] = a;     // reuse xs for transpose staging
                __syncthreads();
                if (t < 4) {
                    (is_seq ? p_arr : q_arr)[i0 + t] = sm.p1.partp[2 * t] + sm.p1.partp[2 * t + 1];
                    (is_seq ? v_arr : w_arr)[i0 + t] = (sm.p1.partv[2 * t] + sm.p1.partv[2 * t + 1]) * (1.f / HDIM);
                }
                if (t < 128) {
                    float4 st = make_float4(sm.p1.xs[0][t], sm.p1.xs[1][t], sm.p1.xs[2][t], sm.p1.xs[3][t]);
                    if (is_seq) *(float4*)&AcT[t * NPOS + i0] = st;
                    else        *(float4*)&BcT[t * NCOL + i0] = st;
                }
            }
            __syncthreads();   // LDS reusable for next pass
        }
    }
    grid_sync(bar, 1u * NBLK);

    // =================== phase 2: fused GEMM + exp + sums (old k2) ===================
    float* rowsum = sums;
    float* segsum = sums + NPOS;
    {
        const int tt = t & 255;
        const int tc = tt & 15;          // col group (4 cols)
        const int tr = tt >> 4;          // row group (2 rows)
        const int kbase = (t >> 8) * 64;
        const int i0 = (b >> 3) * 32;
        const int j0 = (b & 7) * 64;

        #pragma unroll
        for (int u = 0; u < 2; ++u) {
            int fid = t + 512 * u;
            int k = fid >> 3, m4 = fid & 7;
            *(float4*)&sm.s.As[k * AS_STR + 4 * m4] = *(const float4*)&AcT[k * NPOS + i0 + 4 * m4];
        }
        #pragma unroll
        for (int u = 0; u < 4; ++u) {
            int fid = t + 512 * u;
            int k = fid >> 4, n4 = fid & 15;
            *(float4*)&sm.s.Bs[k * BS_STR + 4 * n4] = *(const float4*)&BcT[k * NCOL + j0 + 4 * n4];
        }
        __syncthreads();

        float acc[8] = {0.f, 0.f, 0.f, 0.f, 0.f, 0.f, 0.f, 0.f};
        #pragma unroll 4
        for (int k = kbase; k < kbase + 64; ++k) {
            float2 a2 = *(const float2*)&sm.s.As[k * AS_STR + 2 * tr];
            float4 b4 = *(const float4*)&sm.s.Bs[k * BS_STR + 4 * tc];
            acc[0] += a2.x * b4.x; acc[1] += a2.x * b4.y; acc[2] += a2.x * b4.z; acc[3] += a2.x * b4.w;
            acc[4] += a2.y * b4.x; acc[5] += a2.y * b4.y; acc[6] += a2.y * b4.z; acc[7] += a2.y * b4.w;
        }

        const int seg_lo = segid[i0];
        const int seg_hi = segid[i0 + 31];
        __syncthreads();   // As/Bs done; union region reusable

        if (t >= 256) {
            #pragma unroll
            for (int j = 0; j < 8; ++j) sm.r.comb[j * 256 + tt] = acc[j];
        }
        __syncthreads();

        float e[2][4];
        if (t < 256) {
            #pragma unroll
            for (int j = 0; j < 8; ++j) acc[j] += sm.r.comb[j * 256 + tt];

            const int jj = j0 + 4 * tc;
            float4 q4 = *(const float4*)&q_arr[jj];
            float4 w4 = *(const float4*)&w_arr[jj];
            float rs[2];
            #pragma unroll
            for (int mm = 0; mm < 2; ++mm) {
                const int i = i0 + 2 * tr + mm;
                const float pi = p_arr[i];
                const float vi = v_arr[i];
                e[mm][0] = __expf((pi + q4.x) * rsqrtf(vi + w4.x + acc[4*mm+0] * (2.f/HDIM) + LN_EPS));
                e[mm][1] = __expf((pi + q4.y) * rsqrtf(vi + w4.y + acc[4*mm+1] * (2.f/HDIM) + LN_EPS));
                e[mm][2] = __expf((pi + q4.z) * rsqrtf(vi + w4.z + acc[4*mm+2] * (2.f/HDIM) + LN_EPS));
                e[mm][3] = __expf((pi + q4.w) * rsqrtf(vi + w4.w + acc[4*mm+3] * (2.f/HDIM) + LN_EPS));
                rs[mm] = e[mm][0] + e[mm][1] + e[mm][2] + e[mm][3];
                *(float4*)&E[i * NCOL + jj] = make_float4(e[mm][0], e[mm][1], e[mm][2], e[mm][3]);
            }
            sm.r.redr[(2 * tr + 0) * 16 + tc] = rs[0];
            sm.r.redr[(2 * tr + 1) * 16 + tc] = rs[1];
            #pragma unroll
            for (int u = 0; u < 4; ++u)
                sm.r.redc[(4 * tc + u) * 16 + tr] = e[0][u] + e[1][u];
        }
        __syncthreads();

        if (t < 32) {
            float s = 0.f;
            #pragma unroll
            for (int m = 0; m < 16; ++m) s += sm.r.redr[t * 16 + m];
            atomicAdd(&rowsum[i0 + t], s);
        } else if (t >= 32 && t < 96 && seg_lo == seg_hi) {
            int c = t - 32;
            float s = 0.f;
            #pragma unroll
            for (int m = 0; m < 16; ++m) s += sm.r.redc[c * 16 + m];
            atomicAdd(&segsum[seg_lo * NCOL + j0 + c], s);
        }
        if (seg_lo != seg_hi && t < 256) {
            // generic path: tile crosses a segment boundary (not hit for 8x128)
            #pragma unroll
            for (int mm = 0; mm < 2; ++mm) {
                const int i = i0 + 2 * tr + mm;
                const int sg = segid[i];
                #pragma unroll
                for (int u = 0; u < 4; ++u)
                    atomicAdd(&segsum[sg * NCOL + j0 + 4 * tc + u], e[mm][u]);
            }
        }
    }
    grid_sync(bar, 2u * NBLK);

    // =================== phase 3: out = M_c + M_s - M_c*M_s (old k3) ===================
    {
        const int gid = b * 512 + t;              // 131072 float4 groups
        const int i = gid >> 7;
        const int j = (gid & 127) * 4;

        float4 e4 = *(const float4*)&E[i * NCOL + j];
        const float invr = 1.f / rowsum[i];
        const int sg = segid[i];
        float4 s4 = *(const float4*)&segsum[sg * NCOL + j];

        float4 o;
        { float mc = e4.x * invr, ms = e4.x / s4.x; o.x = mc + ms - mc * ms; }
        { float mc = e4.y * invr, ms = e4.y / s4.y; o.y = mc + ms - mc * ms; }
        { float mc = e4.z * invr, ms = e4.z / s4.z; o.z = mc + ms - mc * ms; }
        { float mc = e4.w * invr, ms = e4.w / s4.w; o.w = mc + ms - mc * ms; }
        *(float4*)&out[i * NCOL + j] = o;
    }
}

// ===========================================================================
extern "C" void kernel_launch(void* const* d_in, const int* in_sizes, int n_in,
                              void* d_out, int out_size, void* d_ws, size_t ws_size,
                              hipStream_t stream) {
    const float* seq_feat = (const float*)d_in[0];
    const float* col_feat = (const float*)d_in[1];
    const int*   lens     = (const int*)d_in[2];
    const float* Ws   = (const float*)d_in[3];
    const float* bs   = (const float*)d_in[4];
    const float* Wc   = (const float*)d_in[5];
    const float* bc   = (const float*)d_in[6];
    const float* Wm   = (const float*)d_in[7];
    const float* bm   = (const float*)d_in[8];
    const float* gam  = (const float*)d_in[9];
    // d_in[10] = beta, d_in[12] = bo: cancel in both normalizations
    const float* Wo   = (const float*)d_in[11];
    float* out = (float*)d_out;
    const int n_seq = in_sizes[2];

    float* ws     = (float*)d_ws;
    float* AcT    = ws;                    // 128*1024
    float* BcT    = AcT + HDIM * NPOS;     // 128*512
    float* p      = BcT + HDIM * NCOL;     // 1024
    float* v      = p + NPOS;              // 1024
    float* q      = v + NPOS;              // 512
    float* w      = q + NCOL;              // 512
    float* sums   = w + NCOL;              // rowsum 1024 + segsum n_seq*512
    float* E      = sums + NPOS + n_seq * NCOL; // 1024*512
    int*   segid  = (int*)(E + NPOS * NCOL);    // 1024 ints
    unsigned int* bar = (unsigned int*)(segid + NPOS);

    // zero the grid-barrier counter each replay (workspace is re-poisoned)
    hipMemsetAsync(bar, 0, sizeof(unsigned int), stream);
    hipLaunchKernelGGL(fused_all, dim3(NBLK), dim3(512), 0, stream,
                       seq_feat, col_feat, Ws, bs, Wc, bc, Wm, bm, gam, Wo,
                       lens, n_seq, AcT, BcT, p, v, q, w, sums, segid, E, out, bar);
}

// Round 3
// 117.862 us; speedup vs baseline: 1.1513x; 1.0450x over previous
//
#include <hip/hip_runtime.h>

#define HDIM 128
#define NPOS 1024
#define NCOL 512
#define LN_EPS 1e-3f
#define NBLK 256

// ---------------------------------------------------------------------------
// Workspace layout (floats):
//   AcT  [128][1024]  centered seq-side A, k-major      (system-scope coherent)
//   BcT  [128][512]   centered col-side B, k-major      (system-scope coherent)
//   p[1024] v[1024] q[512] w[512]                       (system-scope coherent)
//   sums: rowsum[1024] + segsum[n_seq*512]  (device atomics, zeroed in phase 1)
//   segid[1024] (int)                                   (system-scope coherent)
//   bar  (uint)  grid-barrier counter (zeroed by 4-B memset node each replay)
//
// Coherence scheme (replaces agent release/acquire + wbl2/inv, which cost
// ~35us/kernel in round 2): per-XCD L2s are NOT coherent; the coherence point
// is L3. All cross-block data is written with relaxed SYSTEM-scope stores
// (sc0 sc1 -> write-through to L3) and read with SYSTEM-scope loads (bypass
// L2). The grid barrier is then pure arrival counting: __syncthreads drains
// vmcnt (stores at L3), relaxed fetch_add + relaxed poll + s_sleep. No cache
// maintenance instructions anywhere. E is never materialized: each block
// finalizes the tile it computed, e[][] lives in registers across the barrier.
// ---------------------------------------------------------------------------

#define AS_STR 36
#define BS_STR 68

union FusedSmem {
    struct {                       // phase 1
        float xs[4][HDIM];
        float ds[4][HDIM];
        float partm[8], partp[8], partv[8], mus[4];
    } p1;
    struct { float As[128 * AS_STR]; float Bs[128 * BS_STR]; } s;   // phase 2 tiles
    struct { float comb[8 * 256]; float redr[512]; float redc[1024]; } r; // phase 2 reduce
};

__device__ __forceinline__ void st_sys(float* p, float v) {
    __hip_atomic_store(p, v, __ATOMIC_RELAXED, __HIP_MEMORY_SCOPE_SYSTEM);
}
__device__ __forceinline__ float ld_sys(const float* p) {
    return __hip_atomic_load(p, __ATOMIC_RELAXED, __HIP_MEMORY_SCOPE_SYSTEM);
}
__device__ __forceinline__ void st_sys_i(int* p, int v) {
    __hip_atomic_store(p, v, __ATOMIC_RELAXED, __HIP_MEMORY_SCOPE_SYSTEM);
}
__device__ __forceinline__ int ld_sys_i(const int* p) {
    return __hip_atomic_load(p, __ATOMIC_RELAXED, __HIP_MEMORY_SCOPE_SYSTEM);
}

__device__ __forceinline__ int seg_of(int i, const int* __restrict__ lens, int n_seq) {
    int cum = 0;
    for (int s = 0; s < n_seq; ++s) { cum += lens[s]; if (i < cum) return s; }
    return n_seq - 1;
}

// Pure arrival-counting grid barrier: NO release/acquire (no wbl2/buffer_inv).
// Safe because all cross-block data moves via system-scope (L3) accesses and
// __syncthreads drains each thread's vmcnt before the arrival add.
__device__ __forceinline__ void grid_sync(unsigned int* bar, unsigned int need) {
    __syncthreads();                       // all stores/atomics of this block retired
    if (threadIdx.x == 0) {
        __hip_atomic_fetch_add(bar, 1u, __ATOMIC_RELAXED, __HIP_MEMORY_SCOPE_SYSTEM);
        while (__hip_atomic_load(bar, __ATOMIC_RELAXED, __HIP_MEMORY_SCOPE_SYSTEM) < need)
            __builtin_amdgcn_s_sleep(2);
    }
    __syncthreads();
}

extern "C" __global__ void __launch_bounds__(512, 2)
fused_all(const float* __restrict__ seq_feat, const float* __restrict__ col_feat,
          const float* __restrict__ Ws, const float* __restrict__ bsv,
          const float* __restrict__ Wc, const float* __restrict__ bcv,
          const float* __restrict__ Wm, const float* __restrict__ bmv,
          const float* __restrict__ gam, const float* __restrict__ Wo,
          const int* __restrict__ lens, int n_seq,
          float* __restrict__ AcT, float* __restrict__ BcT,
          float* __restrict__ p_arr, float* __restrict__ v_arr,
          float* __restrict__ q_arr, float* __restrict__ w_arr,
          float* __restrict__ sums, int* __restrict__ segid,
          float* __restrict__ out, unsigned int* __restrict__ bar)
{
    __shared__ FusedSmem sm;
    const int t = threadIdx.x;
    const int b = blockIdx.x;

    // =================== phase 1: per-row precompute ===================
    {
        const int h    = t & 127;
        const int r    = t >> 7;
        const int wv   = t >> 6;
        const int lane = t & 63;

        // housekeeping: zero accumulators + fill segid LUT (system-scope)
        {
            const int nsums = NPOS + n_seq * NCOL;
            int idx = b * 512 + t;
            if (idx < nsums) st_sys(&sums[idx], 0.f);
            int idx2 = idx - nsums;
            if (idx2 >= 0 && idx2 < NPOS) st_sys_i(&segid[idx2], seg_of(idx2, lens, n_seq));
        }

        for (int pass = 0; pass < 2; ++pass) {
            const int unit = b + NBLK * pass;          // 384 units over 256 blocks
            if (unit < (NPOS + NCOL) / 4) {
                const bool  is_seq = (unit < NPOS / 4);
                const int   i0 = (is_seq ? unit : unit - NPOS / 4) * 4;
                const float* X  = is_seq ? seq_feat : col_feat;
                const float* W1 = is_seq ? Ws : Wc;
                const float* b1 = is_seq ? bsv : bcv;

                if (t < 128) {
                    int rr = t >> 5, k4 = (t & 31) * 4;
                    *(float4*)&sm.p1.xs[rr][k4] = *(const float4*)&X[(i0 + rr) * HDIM + k4];
                }
                __syncthreads();

                // stage 1: d = relu(x_r . W1[:,h] + b1[h])
                float d;
                {
                    float a0 = 0.f, a1 = 0.f, a2 = 0.f, a3 = 0.f;
                    #pragma unroll 8
                    for (int k = 0; k < HDIM; k += 4) {
                        float4 x = *(const float4*)&sm.p1.xs[r][k];
                        float w0 = W1[(k + 0) * HDIM + h];
                        float w1 = W1[(k + 1) * HDIM + h];
                        float w2 = W1[(k + 2) * HDIM + h];
                        float w3 = W1[(k + 3) * HDIM + h];
                        a0 += x.x * w0; a1 += x.y * w1; a2 += x.z * w2; a3 += x.w * w3;
                    }
                    d = fmaxf(b1[h] + ((a0 + a1) + (a2 + a3)), 0.f);
                }
                sm.p1.ds[r][h] = d;
                __syncthreads();

                // stage 2: aa = d_r . Wm[:,h] (+ bm on col side)
                float aa;
                {
                    float a0 = 0.f, a1 = 0.f, a2 = 0.f, a3 = 0.f;
                    #pragma unroll 8
                    for (int k = 0; k < HDIM; k += 4) {
                        float4 x = *(const float4*)&sm.p1.ds[r][k];
                        float w0 = Wm[(k + 0) * HDIM + h];
                        float w1 = Wm[(k + 1) * HDIM + h];
                        float w2 = Wm[(k + 2) * HDIM + h];
                        float w3 = Wm[(k + 3) * HDIM + h];
                        a0 += x.x * w0; a1 += x.y * w1; a2 += x.z * w2; a3 += x.w * w3;
                    }
                    aa = (is_seq ? 0.f : bmv[h]) + ((a0 + a1) + (a2 + a3));
                }

                // row mean
                {
                    float s = aa;
                    #pragma unroll
                    for (int off = 32; off; off >>= 1) s += __shfl_xor(s, off, 64);
                    if (lane == 0) sm.p1.partm[wv] = s;
                }
                __syncthreads();
                if (t < 4) sm.p1.mus[t] = (sm.p1.partm[2 * t] + sm.p1.partm[2 * t + 1]) * (1.f / HDIM);
                __syncthreads();

                const float a  = aa - sm.p1.mus[r];
                const float gw = gam[h] * Wo[h];

                // p = dot(a, gamma*Wo), v = mean(a^2)
                {
                    float sp = a * gw, sv = a * a;
                    #pragma unroll
                    for (int off = 32; off; off >>= 1) {
                        sp += __shfl_xor(sp, off, 64);
                        sv += __shfl_xor(sv, off, 64);
                    }
                    if (lane == 0) { sm.p1.partp[wv] = sp; sm.p1.partv[wv] = sv; }
                }
                sm.p1.xs[r][h] = a;     // reuse xs for transpose staging
                __syncthreads();
                if (t < 4) {
                    st_sys(&(is_seq ? p_arr : q_arr)[i0 + t], sm.p1.partp[2 * t] + sm.p1.partp[2 * t + 1]);
                    st_sys(&(is_seq ? v_arr : w_arr)[i0 + t], (sm.p1.partv[2 * t] + sm.p1.partv[2 * t + 1]) * (1.f / HDIM));
                }
                if (t < 128) {
                    float* dst = is_seq ? &AcT[t * NPOS + i0] : &BcT[t * NCOL + i0];
                    st_sys(dst + 0, sm.p1.xs[0][t]);
                    st_sys(dst + 1, sm.p1.xs[1][t]);
                    st_sys(dst + 2, sm.p1.xs[2][t]);
                    st_sys(dst + 3, sm.p1.xs[3][t]);
                }
            }
            __syncthreads();   // LDS reusable for next pass
        }
    }
    grid_sync(bar, 1u * NBLK);

    // =================== phase 2: fused GEMM + exp + sums ===================
    float* rowsum = sums;
    float* segsum = sums + NPOS;
    const int tt = t & 255;
    const int tc = tt & 15;          // col group (4 cols)
    const int tr = tt >> 4;          // row group (2 rows)
    const int i0 = (b >> 3) * 32;
    const int j0 = (b & 7) * 64;
    float e[2][4] = {};
    {
        const int kbase = (t >> 8) * 64;

        // stage tiles via system-scope loads (sourced from L3)
        #pragma unroll
        for (int u = 0; u < 2; ++u) {
            int fid = t + 512 * u;
            int k = fid >> 3, m4 = fid & 7;
            const float* src = &AcT[k * NPOS + i0 + 4 * m4];
            float4 tmp = make_float4(ld_sys(src + 0), ld_sys(src + 1), ld_sys(src + 2), ld_sys(src + 3));
            *(float4*)&sm.s.As[k * AS_STR + 4 * m4] = tmp;
        }
        #pragma unroll
        for (int u = 0; u < 4; ++u) {
            int fid = t + 512 * u;
            int k = fid >> 4, n4 = fid & 15;
            const float* src = &BcT[k * NCOL + j0 + 4 * n4];
            float4 tmp = make_float4(ld_sys(src + 0), ld_sys(src + 1), ld_sys(src + 2), ld_sys(src + 3));
            *(float4*)&sm.s.Bs[k * BS_STR + 4 * n4] = tmp;
        }
        __syncthreads();

        float acc[8] = {0.f, 0.f, 0.f, 0.f, 0.f, 0.f, 0.f, 0.f};
        #pragma unroll 4
        for (int k = kbase; k < kbase + 64; ++k) {
            float2 a2 = *(const float2*)&sm.s.As[k * AS_STR + 2 * tr];
            float4 b4 = *(const float4*)&sm.s.Bs[k * BS_STR + 4 * tc];
            acc[0] += a2.x * b4.x; acc[1] += a2.x * b4.y; acc[2] += a2.x * b4.z; acc[3] += a2.x * b4.w;
            acc[4] += a2.y * b4.x; acc[5] += a2.y * b4.y; acc[6] += a2.y * b4.z; acc[7] += a2.y * b4.w;
        }

        const int seg_lo = ld_sys_i(&segid[i0]);
        const int seg_hi = ld_sys_i(&segid[i0 + 31]);
        __syncthreads();   // As/Bs done; union region reusable

        if (t >= 256) {
            #pragma unroll
            for (int j = 0; j < 8; ++j) sm.r.comb[j * 256 + tt] = acc[j];
        }
        __syncthreads();

        if (t < 256) {
            #pragma unroll
            for (int j = 0; j < 8; ++j) acc[j] += sm.r.comb[j * 256 + tt];

            const int jj = j0 + 4 * tc;
            float4 q4 = make_float4(ld_sys(&q_arr[jj]), ld_sys(&q_arr[jj + 1]),
                                    ld_sys(&q_arr[jj + 2]), ld_sys(&q_arr[jj + 3]));
            float4 w4 = make_float4(ld_sys(&w_arr[jj]), ld_sys(&w_arr[jj + 1]),
                                    ld_sys(&w_arr[jj + 2]), ld_sys(&w_arr[jj + 3]));
            float rs[2];
            #pragma unroll
            for (int mm = 0; mm < 2; ++mm) {
                const int i = i0 + 2 * tr + mm;
                const float pi = ld_sys(&p_arr[i]);
                const float vi = ld_sys(&v_arr[i]);
                e[mm][0] = __expf((pi + q4.x) * rsqrtf(vi + w4.x + acc[4*mm+0] * (2.f/HDIM) + LN_EPS));
                e[mm][1] = __expf((pi + q4.y) * rsqrtf(vi + w4.y + acc[4*mm+1] * (2.f/HDIM) + LN_EPS));
                e[mm][2] = __expf((pi + q4.z) * rsqrtf(vi + w4.z + acc[4*mm+2] * (2.f/HDIM) + LN_EPS));
                e[mm][3] = __expf((pi + q4.w) * rsqrtf(vi + w4.w + acc[4*mm+3] * (2.f/HDIM) + LN_EPS));
                rs[mm] = e[mm][0] + e[mm][1] + e[mm][2] + e[mm][3];
            }
            sm.r.redr[(2 * tr + 0) * 16 + tc] = rs[0];
            sm.r.redr[(2 * tr + 1) * 16 + tc] = rs[1];
            #pragma unroll
            for (int u = 0; u < 4; ++u)
                sm.r.redc[(4 * tc + u) * 16 + tr] = e[0][u] + e[1][u];
        }
        __syncthreads();

        if (t < 32) {
            float s = 0.f;
            #pragma unroll
            for (int m = 0; m < 16; ++m) s += sm.r.redr[t * 16 + m];
            atomicAdd(&rowsum[i0 + t], s);
        } else if (t >= 32 && t < 96 && seg_lo == seg_hi) {
            int c = t - 32;
            float s = 0.f;
            #pragma unroll
            for (int m = 0; m < 16; ++m) s += sm.r.redc[c * 16 + m];
            atomicAdd(&segsum[seg_lo * NCOL + j0 + c], s);
        }
        if (seg_lo != seg_hi && t < 256) {
            // generic path: tile crosses a segment boundary (not hit for 8x128)
            #pragma unroll
            for (int mm = 0; mm < 2; ++mm) {
                const int i = i0 + 2 * tr + mm;
                const int sg = ld_sys_i(&segid[i]);
                #pragma unroll
                for (int u = 0; u < 4; ++u)
                    atomicAdd(&segsum[sg * NCOL + j0 + 4 * tc + u], e[mm][u]);
            }
        }
    }
    grid_sync(bar, 2u * NBLK);

    // ====== phase 3: finalize own tile from registers (E never materialized) ======
    if (t < 256) {
        const int jj = j0 + 4 * tc;
        #pragma unroll
        for (int mm = 0; mm < 2; ++mm) {
            const int i = i0 + 2 * tr + mm;
            const float invr = 1.f / ld_sys(&rowsum[i]);
            const int sg = ld_sys_i(&segid[i]);
            const float s0 = ld_sys(&segsum[sg * NCOL + jj + 0]);
            const float s1 = ld_sys(&segsum[sg * NCOL + jj + 1]);
            const float s2 = ld_sys(&segsum[sg * NCOL + jj + 2]);
            const float s3 = ld_sys(&segsum[sg * NCOL + jj + 3]);
            float4 o;
            { float mc = e[mm][0] * invr, ms = e[mm][0] / s0; o.x = mc + ms - mc * ms; }
            { float mc = e[mm][1] * invr, ms = e[mm][1] / s1; o.y = mc + ms - mc * ms; }
            { float mc = e[mm][2] * invr, ms = e[mm][2] / s2; o.z = mc + ms - mc * ms; }
            { float mc = e[mm][3] * invr, ms = e[mm][3] / s3; o.w = mc + ms - mc * ms; }
            *(float4*)&out[i * NCOL + jj] = o;
        }
    }
}

// ===========================================================================
extern "C" void kernel_launch(void* const* d_in, const int* in_sizes, int n_in,
                              void* d_out, int out_size, void* d_ws, size_t ws_size,
                              hipStream_t stream) {
    const float* seq_feat = (const float*)d_in[0];
    const float* col_feat = (const float*)d_in[1];
    const int*   lens     = (const int*)d_in[2];
    const float* Ws   = (const float*)d_in[3];
    const float* bs   = (const float*)d_in[4];
    const float* Wc   = (const float*)d_in[5];
    const float* bc   = (const float*)d_in[6];
    const float* Wm   = (const float*)d_in[7];
    const float* bm   = (const float*)d_in[8];
    const float* gam  = (const float*)d_in[9];
    // d_in[10] = beta, d_in[12] = bo: cancel in both normalizations
    const float* Wo   = (const float*)d_in[11];
    float* out = (float*)d_out;
    const int n_seq = in_sizes[2];

    float* ws     = (float*)d_ws;
    float* AcT    = ws;                    // 128*1024
    float* BcT    = AcT + HDIM * NPOS;     // 128*512
    float* p      = BcT + HDIM * NCOL;     // 1024
    float* v      = p + NPOS;              // 1024
    float* q      = v + NPOS;              // 512
    float* w      = q + NCOL;              // 512
    float* sums   = w + NCOL;              // rowsum 1024 + segsum n_seq*512
    int*   segid  = (int*)(sums + NPOS + n_seq * NCOL); // 1024 ints
    unsigned int* bar = (unsigned int*)(segid + NPOS);

    // zero the grid-barrier counter each replay (workspace is re-poisoned)
    hipMemsetAsync(bar, 0, sizeof(unsigned int), stream);
    hipLaunchKernelGGL(fused_all, dim3(NBLK), dim3(512), 0, stream,
                       seq_feat, col_feat, Ws, bs, Wc, bc, Wm, bm, gam, Wo,
                       lens, n_seq, AcT, BcT, p, v, q, w, sums, segid, out, bar);
}